// Round 6
// baseline (126.507 us; speedup 1.0000x reference)
//
#include <hip/hip_runtime.h>
#include <hip/hip_bf16.h>

#define B 8
#define T 2048
#define C 96
#define NH 3
#define HD 32
#define FFD 2048
#define HALF_W 32
#define BT (B*T)

typedef __hip_bfloat16 bf16;
typedef __attribute__((ext_vector_type(8))) short short8;
typedef __attribute__((ext_vector_type(4))) short short4v;
typedef __attribute__((ext_vector_type(16))) float floatx16;

__device__ __forceinline__ short f2bs(float v){
    __hip_bfloat16 h = __float2bfloat16(v);
    return *reinterpret_cast<short*>(&h);
}
__device__ __forceinline__ float bs2f(short s){
    unsigned u = ((unsigned)(unsigned short)s) << 16;
    return __uint_as_float(u);
}
__device__ __forceinline__ int imin(int a, int b){ return a < b ? a : b; }
__device__ __forceinline__ int imax(int a, int b){ return a > b ? a : b; }
__device__ __forceinline__ short8 ld_b64x2(const short* p){
    short4v a = *(const short4v*)p;
    short4v b = *(const short4v*)(p + 4);
    short8 v;
    v[0]=a[0]; v[1]=a[1]; v[2]=a[2]; v[3]=a[3];
    v[4]=b[0]; v[5]=b[1]; v[6]=b[2]; v[7]=b[3];
    return v;
}
__device__ __forceinline__ int4 exch_pair(int a0,int a1,int b0,int b1,int hq){
    int ra0=__shfl_xor(a0,32), ra1=__shfl_xor(a1,32);
    int rb0=__shfl_xor(b0,32), rb1=__shfl_xor(b1,32);
    int4 s;
    s.x = hq ? rb0 : a0;
    s.y = hq ? rb1 : a1;
    s.z = hq ? b0  : ra0;
    s.w = hq ? b1  : ra1;
    return s;
}

// ---------------- K0: convert weights to bf16 in FRAGMENT-MAJOR (swizzled) layout ----
__global__ void cvtw_kernel(const float* __restrict__ wq, const float* __restrict__ wo,
                            const float* __restrict__ w1, const float* __restrict__ w2,
                            bf16* __restrict__ dst){
    int i = blockIdx.x*256 + threadIdx.x;
    if(i < 27648){
        int e = i&7, lane = (i>>3)&63, r = i>>9;
        int ks = r%6, ot = r/6;
        int o = ot*32 + (lane&31);
        int k = ks*16 + (lane>>5)*8 + e;
        dst[i] = __float2bfloat16(wq[o*96 + k]);
    } else if(i < 36864){
        int j = i - 27648;
        int e = j&7, lane = (j>>3)&63, r = j>>9;
        int ks = r%6, ct = r/6;
        int c = ct*32 + (lane&31);
        int k = ks*16 + (lane>>5)*8 + e;
        dst[i] = __float2bfloat16(wo[c*96 + k]);
    } else if(i < 233472){
        int j = i - 36864;
        int e = j&7, lane = (j>>3)&63, r = j>>9;
        int ks = r%6; r /= 6;
        int w = r%4, jt = r/4;
        int row = jt*128 + w*32 + (lane&31);
        int k = ks*16 + (lane>>5)*8 + e;
        dst[i] = __float2bfloat16(w1[row*96 + k]);
    } else if(i < 430080){
        int j = i - 233472;
        int e = j&7, lane = (j>>3)&63, r = j>>9;
        int ct = r%3; r /= 3;
        int g = r%2; r /= 2;
        int w = r%4, jt = r/4;
        int c = ct*32 + (lane&31);
        int k = jt*128 + w*32 + g*16 + (lane>>5)*8 + e;
        dst[i] = __float2bfloat16(w2[c*FFD + k]);
    }
}

// ---------------- K1: QKV projection, MFMA (proven) ----------------
__global__ __launch_bounds__(256) void qkv_kernel(
    const float* __restrict__ x, const bf16* __restrict__ wqs,
    const float* __restrict__ bias, bf16* __restrict__ qswz,
    bf16* __restrict__ kswz, bf16* __restrict__ vbuf){
    __shared__ float xs[96*36];
    int b  = blockIdx.x >> 6;
    int tt = blockIdx.x & 63;            // token tile
    int t0 = tt * 32;
    for(int e = threadIdx.x; e < 96*8; e += 256){
        int c = e >> 3, t4 = e & 7;
        *(float4*)(xs + c*36 + t4*4) =
            *(const float4*)(x + (size_t)b*C*T + (size_t)c*T + t0 + t4*4);
    }
    __syncthreads();
    const int w = threadIdx.x >> 6, lane = threadIdx.x & 63;
    const int lm = lane & 31, hq = lane >> 5;
    short8 bfr[6];
    #pragma unroll
    for(int ks = 0; ks < 6; ++ks){
        short8 v;
        #pragma unroll
        for(int i = 0; i < 8; ++i)
            v[i] = f2bs(xs[(ks*16 + hq*8 + i)*36 + lm]);
        bfr[ks] = v;
    }
    int nacc = (w == 0) ? 3 : 2;
    int ots[3] = {w, w+4, 8};
    floatx16 acc[3];
    #pragma unroll
    for(int i = 0; i < 3; ++i)
        #pragma unroll
        for(int r = 0; r < 16; ++r) acc[i][r] = 0.f;
    #pragma unroll
    for(int i = 0; i < 3; ++i){
        if(i < nacc){
            #pragma unroll
            for(int ks = 0; ks < 6; ++ks){
                short8 af = *(const short8*)((const short*)wqs
                              + (size_t)(ots[i]*6 + ks)*512 + lane*8);
                acc[i] = __builtin_amdgcn_mfma_f32_32x32x16_bf16(af, bfr[ks], acc[i], 0,0,0);
            }
        }
    }
    #pragma unroll
    for(int i = 0; i < 3; ++i){
        if(i < nacc){
            int ot = ots[i];
            int pkq[4][2];
            #pragma unroll
            for(int q = 0; q < 4; ++q){
                float4 bv = *(const float4*)(bias + ot*32 + 8*q + 4*hq);
                short4v t;
                t[0] = f2bs(acc[i][4*q+0] + bv.x);
                t[1] = f2bs(acc[i][4*q+1] + bv.y);
                t[2] = f2bs(acc[i][4*q+2] + bv.z);
                t[3] = f2bs(acc[i][4*q+3] + bv.w);
                int2 u = *(int2*)&t;
                pkq[q][0] = u.x; pkq[q][1] = u.y;
            }
            if(ot < 6){
                int type = ot/3, hh = ot%3;
                short* base = (short*)(type == 0 ? qswz : kswz)
                            + ((size_t)(b*NH + hh)*64 + tt)*1024 + lane*8;
                #pragma unroll
                for(int g = 0; g < 2; ++g){
                    int a0 = pkq[2*g][0],   a1 = pkq[2*g][1];
                    int b0 = pkq[2*g+1][0], b1v = pkq[2*g+1][1];
                    int ra0 = __shfl_xor(a0, 32),  ra1 = __shfl_xor(a1, 32);
                    int rb0 = __shfl_xor(b0, 32),  rb1 = __shfl_xor(b1v, 32);
                    int4 sfi;
                    sfi.x = hq ? rb0 : a0;
                    sfi.y = hq ? rb1 : a1;
                    sfi.z = hq ? b0  : ra0;
                    sfi.w = hq ? b1v : ra1;
                    *(int4*)(base + g*512) = sfi;
                }
            } else {
                int hh = ot - 6;
                short* rowp = (short*)vbuf + ((size_t)(b*NH + hh)*T + t0 + lm)*32;
                #pragma unroll
                for(int q = 0; q < 4; ++q){
                    int2 u; u.x = pkq[q][0]; u.y = pkq[q][1];
                    *(int2*)(rowp + 8*q + 4*hq) = u;
                }
            }
        }
    }
}

// ---------------- K2: FUSED attention + outproj + residual + LN1 (proven) ---
__global__ __launch_bounds__(192) void attn_op_kernel(
    const bf16* __restrict__ qswz, const bf16* __restrict__ kswz,
    const bf16* __restrict__ vbuf, const bf16* __restrict__ wos,
    const float* __restrict__ bias, const float* __restrict__ x,
    const float* __restrict__ g1, const float* __restrict__ bb1,
    bf16* __restrict__ h1b){
    __shared__ __align__(16) short VtS[3*3200];
    __shared__ __align__(16) short PtS[3][3200];
    __shared__ float LsS[3][32];
    __shared__ __align__(16) short ctxS[32*100];
    __shared__ float red1[2][3][32];
    const int tid = threadIdx.x;
    const int w = tid / 64, lane = tid & 63;
    const int lm = lane & 31, hq = lane >> 5;
    int b  = blockIdx.x >> 6;
    int tt = blockIdx.x & 63;
    int t0 = tt * 32;

    short8 wof[6];
    #pragma unroll
    for(int ks = 0; ks < 6; ++ks)
        wof[ks] = *(const short8*)((const short*)wos + (size_t)(w*6 + ks)*512 + lane*8);

    for(int e = tid; e < 576; e += 192){
        int hh = e / 192, rem = e % 192;
        int kp = rem >> 2, d8 = rem & 3;
        const short* vb = (const short*)vbuf + (size_t)(b*NH + hh)*T*32;
        int sa = imin(imax(t0 - 32 + 2*kp, 0), T-1);
        int sb = imin(imax(t0 - 32 + 2*kp + 1, 0), T-1);
        short8 va = *(const short8*)(vb + (size_t)sa*32 + d8*8);
        short8 v2 = *(const short8*)(vb + (size_t)sb*32 + d8*8);
        #pragma unroll
        for(int j = 0; j < 8; ++j){
            int val = (int)(unsigned short)va[j] | ((int)(unsigned short)v2[j] << 16);
            *(int*)(VtS + hh*3200 + (d8*8 + j)*100 + 2*kp) = val;
        }
    }
    const short* qsw = (const short*)qswz + ((size_t)(b*NH + w)*64 + tt)*1024 + lane*8;
    short8 qf0 = *(const short8*)(qsw);
    short8 qf1 = *(const short8*)(qsw + 512);
    floatx16 S[3];
    #pragma unroll
    for(int sub = 0; sub < 3; ++sub){
        int kt = imin(imax(tt - 1 + sub, 0), 63);
        const short* ksw = (const short*)kswz + ((size_t)(b*NH + w)*64 + kt)*1024 + lane*8;
        short8 kf0 = *(const short8*)(ksw);
        short8 kf1 = *(const short8*)(ksw + 512);
        floatx16 z;
        #pragma unroll
        for(int r = 0; r < 16; ++r) z[r] = 0.f;
        z = __builtin_amdgcn_mfma_f32_32x32x16_bf16(kf0, qf0, z, 0,0,0);
        z = __builtin_amdgcn_mfma_f32_32x32x16_bf16(kf1, qf1, z, 0,0,0);
        S[sub] = z;
    }
    const float scale = 0.17677669529663687f;
    float part = 0.f;
    #pragma unroll
    for(int sub = 0; sub < 3; ++sub){
        #pragma unroll
        for(int r = 0; r < 16; ++r){
            int key_local = sub*32 + (r&3) + 8*(r>>2) + 4*hq;
            int s_glob = t0 - 32 + key_local;
            int rel = key_local - lm;
            bool ok = (rel >= 0) && (rel <= 64) && (s_glob >= 0) && (s_glob < T);
            float p = ok ? __expf(S[sub][r]*scale) : 0.f;
            S[sub][r] = p;
            part += p;
        }
    }
    float ltot = part + __shfl_xor(part, 32);
    if(hq == 0) LsS[w][lm] = ltot;
    #pragma unroll
    for(int sub = 0; sub < 3; ++sub){
        #pragma unroll
        for(int q4 = 0; q4 < 4; ++q4){
            int kbase = sub*32 + 8*q4 + 4*hq;
            short4v pk;
            pk[0] = f2bs(S[sub][4*q4+0]);
            pk[1] = f2bs(S[sub][4*q4+1]);
            pk[2] = f2bs(S[sub][4*q4+2]);
            pk[3] = f2bs(S[sub][4*q4+3]);
            *(short4v*)(PtS[w] + lm*100 + kbase) = pk;
        }
    }
    __syncthreads();
    floatx16 O;
    #pragma unroll
    for(int r = 0; r < 16; ++r) O[r] = 0.f;
    #pragma unroll
    for(int ks = 0; ks < 6; ++ks){
        short8 pa = ld_b64x2(PtS[w] + lm*100 + ks*16 + hq*8);
        short8 vf = ld_b64x2(VtS + w*3200 + lm*100 + ks*16 + hq*8);
        O = __builtin_amdgcn_mfma_f32_32x32x16_bf16(pa, vf, O, 0,0,0);
    }
    #pragma unroll
    for(int r = 0; r < 16; ++r){
        int qr = (r&3) + 8*(r>>2) + 4*hq;
        float linv = 1.f / LsS[w][qr];
        ctxS[qr*100 + w*32 + lm] = f2bs(O[r]*linv);
    }
    __syncthreads();

    short8 bfr[6];
    #pragma unroll
    for(int ks = 0; ks < 6; ++ks)
        bfr[ks] = ld_b64x2(ctxS + lm*100 + ks*16 + hq*8);
    floatx16 acc;
    #pragma unroll
    for(int r = 0; r < 16; ++r) acc[r] = 0.f;
    #pragma unroll
    for(int ks = 0; ks < 6; ++ks)
        acc = __builtin_amdgcn_mfma_f32_32x32x16_bf16(wof[ks], bfr[ks], acc, 0,0,0);
    float vals[16];
    float p1 = 0.f, p2 = 0.f;
    #pragma unroll
    for(int q = 0; q < 4; ++q){
        int c = w*32 + 8*q + 4*hq;
        float4 bv = *(const float4*)(bias + c);
        float bva[4] = {bv.x, bv.y, bv.z, bv.w};
        #pragma unroll
        for(int r = 0; r < 4; ++r){
            float xv = x[(size_t)b*C*T + (size_t)(c + r)*T + t0 + lm];
            float v = acc[4*q+r] + bva[r] + xv;
            vals[4*q+r] = v;
            p1 += v; p2 += v*v;
        }
    }
    p1 += __shfl_xor(p1, 32);
    p2 += __shfl_xor(p2, 32);
    if(hq == 0){ red1[0][w][lm] = p1; red1[1][w][lm] = p2; }
    __syncthreads();
    float s  = red1[0][0][lm] + red1[0][1][lm] + red1[0][2][lm];
    float s2 = red1[1][0][lm] + red1[1][1][lm] + red1[1][2][lm];
    float mu = s * (1.0f/96.0f);
    float rstd = rsqrtf(s2*(1.0f/96.0f) - mu*mu + 1e-5f);
    int row = b*T + t0 + lm;
    #pragma unroll
    for(int q = 0; q < 4; ++q){
        int c = w*32 + 8*q + 4*hq;
        float4 gv = *(const float4*)(g1 + c);
        float4 bv = *(const float4*)(bb1 + c);
        float ga[4] = {gv.x, gv.y, gv.z, gv.w};
        float ba[4] = {bv.x, bv.y, bv.z, bv.w};
        short4v pk;
        #pragma unroll
        for(int r = 0; r < 4; ++r)
            pk[r] = f2bs((vals[4*q+r] - mu)*rstd*ga[r] + ba[r]);
        *(short4v*)((short*)h1b + (size_t)row*96 + c) = pk;
    }
}

// ---------------- K3: FF, 64-token tiles (mt=2), 256 blocks x 4 waves ---------------
// Each weight fragment amortized over 64 tokens -> L2 weight traffic halves vs
// 32-token tiles (393 -> 197 MB). w1 prefetch double-buffered across J-iters; w2
// loaded at iteration top (covered by FF1 chain). Plain-LDS staged partial reduce
// (52 KB REDP reused for mt=0 then mt=1) -> 55 KB LDS -> 2 blocks/CU.
__global__ __launch_bounds__(256, 2) void ff_kernel(
    const bf16* __restrict__ h1b,
    const bf16* __restrict__ w1s, const float* __restrict__ b1,
    const bf16* __restrict__ w2s, const float* __restrict__ b2,
    const float* __restrict__ g2, const float* __restrict__ bt2,
    const float* __restrict__ gf, const float* __restrict__ btf,
    float* __restrict__ out){
    // LDS: REDP f32[12][1088] [0,52224)  (ZT f32[96*68]=26112 aliased at [0,26112))
    //      RED1 f32[2][2][96] [52224,53760) ; RED2 f32[2][2][96] [53760,55296)
    __shared__ __align__(16) char smem[55296];
    float* REDP = (float*)smem;
    float* ZT   = (float*)smem;
    float* RED1 = (float*)(smem + 52224);
    float* RED2 = (float*)(smem + 53760);

    const int tid = threadIdx.x;
    const int w4 = tid >> 6, lane = tid & 63;
    const int lm = lane & 31, hq = lane >> 5;
    const int r0 = blockIdx.x * 64;
    const short* h1p = (const short*)h1b;

    short8 hf[2][6];
    #pragma unroll
    for(int mt = 0; mt < 2; ++mt)
        #pragma unroll
        for(int ks = 0; ks < 6; ++ks)
            hf[mt][ks] = *(const short8*)(h1p + (size_t)(r0 + mt*32 + lm)*96 + ks*16 + hq*8);

    floatx16 acc2[2][3];
    #pragma unroll
    for(int mt = 0; mt < 2; ++mt)
        #pragma unroll
        for(int i = 0; i < 3; ++i)
            #pragma unroll
            for(int r = 0; r < 16; ++r) acc2[mt][i][r] = 0.f;

    const short* w1b = (const short*)w1s + lane*8;
    const short* w2b = (const short*)w2s + lane*8;
    short8 cw1[6];
    #pragma unroll
    for(int ks = 0; ks < 6; ++ks)
        cw1[ks] = *(const short8*)(w1b + (size_t)(w4*6 + ks)*512);

    for(int it = 0; it < 16; ++it){
        const int J  = w4 + it*4;
        const int Jn = (it < 15) ? J + 4 : w4;
        // w2 for THIS iter: issued first, consumed after FF1 chain (~400 cy later)
        short8 w2f[6];
        #pragma unroll
        for(int g = 0; g < 2; ++g)
            #pragma unroll
            for(int ct = 0; ct < 3; ++ct)
                w2f[g*3 + ct] = *(const short8*)(w2b + (size_t)((J*2 + g)*3 + ct)*512);
        // w1 prefetch for NEXT iter
        short8 nw1[6];
        #pragma unroll
        for(int ks = 0; ks < 6; ++ks)
            nw1[ks] = *(const short8*)(w1b + (size_t)(Jn*6 + ks)*512);
        floatx16 a0, a1;
        #pragma unroll
        for(int r = 0; r < 16; ++r){ a0[r] = 0.f; a1[r] = 0.f; }
        #pragma unroll
        for(int ks = 0; ks < 6; ++ks){
            a0 = __builtin_amdgcn_mfma_f32_32x32x16_bf16(cw1[ks], hf[0][ks], a0, 0,0,0);
            a1 = __builtin_amdgcn_mfma_f32_32x32x16_bf16(cw1[ks], hf[1][ks], a1, 0,0,0);
        }
        int pk[2][4][2];
        #pragma unroll
        for(int q = 0; q < 4; ++q){
            float4 bv = *(const float4*)(b1 + J*32 + 8*q + 4*hq);
            float bva[4] = {bv.x, bv.y, bv.z, bv.w};
            short4v t0v, t1v;
            #pragma unroll
            for(int r = 0; r < 4; ++r){
                float v0 = a0[4*q+r] + bva[r];
                float v1 = a1[4*q+r] + bva[r];
                t0v[r] = f2bs(v0 > 0.f ? v0 : 0.f);
                t1v[r] = f2bs(v1 > 0.f ? v1 : 0.f);
            }
            int2 u0 = *(int2*)&t0v; int2 u1 = *(int2*)&t1v;
            pk[0][q][0] = u0.x; pk[0][q][1] = u0.y;
            pk[1][q][0] = u1.x; pk[1][q][1] = u1.y;
        }
        #pragma unroll
        for(int g = 0; g < 2; ++g){
            #pragma unroll
            for(int mt = 0; mt < 2; ++mt){
                int4 sfi = exch_pair(pk[mt][2*g][0], pk[mt][2*g][1],
                                     pk[mt][2*g+1][0], pk[mt][2*g+1][1], hq);
                short8 sf = *(short8*)&sfi;
                #pragma unroll
                for(int ct = 0; ct < 3; ++ct)
                    acc2[mt][ct] = __builtin_amdgcn_mfma_f32_32x32x16_bf16(
                                       w2f[g*3+ct], sf, acc2[mt][ct], 0,0,0);
            }
        }
        #pragma unroll
        for(int ks = 0; ks < 6; ++ks) cw1[ks] = nw1[ks];
    }

    // ---- staged partial reduce: REDP pass per mt, consumed by waves 0..2 (ct=w4)
    float fv[2][16];
    float e1m[2], e2m[2];
    #pragma unroll
    for(int mt = 0; mt < 2; ++mt){
        #pragma unroll
        for(int ct = 0; ct < 3; ++ct)
            #pragma unroll
            for(int q = 0; q < 4; ++q)
                #pragma unroll
                for(int r = 0; r < 4; ++r)
                    REDP[(w4*3 + ct)*1088 + lane*17 + 4*q + r] = acc2[mt][ct][4*q+r];
        __syncthreads();                               // dump complete
        if(w4 < 3){
            float e1 = 0.f, e2 = 0.f;
            #pragma unroll
            for(int q = 0; q < 4; ++q){
                int cb = w4*32 + 8*q + 4*hq;
                float4 bv = *(const float4*)(b2 + cb);
                float bva[4] = {bv.x, bv.y, bv.z, bv.w};
                short4v hv = *(const short4v*)(h1p + (size_t)(r0 + mt*32 + lm)*96 + cb);
                #pragma unroll
                for(int r = 0; r < 4; ++r){
                    float v = REDP[(0*3 + w4)*1088 + lane*17 + 4*q + r]
                            + REDP[(1*3 + w4)*1088 + lane*17 + 4*q + r]
                            + REDP[(2*3 + w4)*1088 + lane*17 + 4*q + r]
                            + REDP[(3*3 + w4)*1088 + lane*17 + 4*q + r]
                            + bva[r] + bs2f(hv[r]);
                    fv[mt][4*q+r] = v;
                    e1 += v; e2 += v*v;
                }
            }
            e1m[mt] = e1 + __shfl_xor(e1, 32);
            e2m[mt] = e2 + __shfl_xor(e2, 32);
        }
        __syncthreads();                               // reads done; REDP reusable
    }
    if(w4 < 3 && hq == 0){
        #pragma unroll
        for(int mt = 0; mt < 2; ++mt){
            RED1[mt*192 + w4*32 + lm] = e1m[mt];
            RED1[mt*192 + 96 + w4*32 + lm] = e2m[mt];
        }
    }
    __syncthreads();                                   // RED1 ready
    float f1m[2], f2m[2];
    if(w4 < 3){
        #pragma unroll
        for(int mt = 0; mt < 2; ++mt){
            float s  = RED1[mt*192 + lm] + RED1[mt*192 + 32 + lm] + RED1[mt*192 + 64 + lm];
            float s2 = RED1[mt*192 + 96 + lm] + RED1[mt*192 + 128 + lm] + RED1[mt*192 + 160 + lm];
            float mu = s * (1.0f/96.0f);
            float rstd = rsqrtf(s2*(1.0f/96.0f) - mu*mu + 1e-5f);
            float f1 = 0.f, f2 = 0.f;
            #pragma unroll
            for(int q = 0; q < 4; ++q){
                int c = w4*32 + 8*q + 4*hq;
                float4 gv = *(const float4*)(g2 + c);
                float4 bv = *(const float4*)(bt2 + c);
                float ga[4] = {gv.x, gv.y, gv.z, gv.w};
                float ba[4] = {bv.x, bv.y, bv.z, bv.w};
                #pragma unroll
                for(int r = 0; r < 4; ++r){
                    float y = (fv[mt][4*q+r] - mu)*rstd*ga[r] + ba[r];
                    fv[mt][4*q+r] = y;
                    f1 += y; f2 += y*y;
                }
            }
            f1m[mt] = f1 + __shfl_xor(f1, 32);
            f2m[mt] = f2 + __shfl_xor(f2, 32);
        }
        if(hq == 0){
            #pragma unroll
            for(int mt = 0; mt < 2; ++mt){
                RED2[mt*192 + w4*32 + lm] = f1m[mt];
                RED2[mt*192 + 96 + w4*32 + lm] = f2m[mt];
            }
        }
    }
    __syncthreads();                                   // RED2 ready; REDP dead
    if(w4 < 3){
        #pragma unroll
        for(int mt = 0; mt < 2; ++mt){
            float s  = RED2[mt*192 + lm] + RED2[mt*192 + 32 + lm] + RED2[mt*192 + 64 + lm];
            float s2 = RED2[mt*192 + 96 + lm] + RED2[mt*192 + 128 + lm] + RED2[mt*192 + 160 + lm];
            float mu = s * (1.0f/96.0f);
            float rstd = rsqrtf(s2*(1.0f/96.0f) - mu*mu + 1e-5f);
            #pragma unroll
            for(int q = 0; q < 4; ++q){
                int c = w4*32 + 8*q + 4*hq;
                float4 gv = *(const float4*)(gf + c);
                float4 bv = *(const float4*)(btf + c);
                float ga[4] = {gv.x, gv.y, gv.z, gv.w};
                float ba[4] = {bv.x, bv.y, bv.z, bv.w};
                #pragma unroll
                for(int r = 0; r < 4; ++r)
                    ZT[(c + r)*68 + mt*32 + lm] = (fv[mt][4*q+r] - mu)*rstd*ga[r] + ba[r];
            }
        }
    }
    __syncthreads();                                   // ZT ready
    const int bb = r0 / T, t0g = r0 % T;
    float* ob = out + (size_t)bb*C*T + t0g;
    for(int e = tid; e < 96*16; e += 256){
        int c = e >> 4, tg = e & 15;
        *(float4*)(ob + (size_t)c*T + tg*4) = *(const float4*)(ZT + c*68 + tg*4);
    }
}

extern "C" void kernel_launch(void* const* d_in, const int* in_sizes, int n_in,
                              void* d_out, int out_size, void* d_ws, size_t ws_size,
                              hipStream_t stream) {
    const float* x     = (const float*)d_in[0];
    const float* w_qkv = (const float*)d_in[1];
    const float* b_qkv = (const float*)d_in[2];
    const float* w_out = (const float*)d_in[3];
    const float* b_out = (const float*)d_in[4];
    const float* ln1_g = (const float*)d_in[5];
    const float* ln1_b = (const float*)d_in[6];
    const float* w_ff1 = (const float*)d_in[7];
    const float* b_ff1 = (const float*)d_in[8];
    const float* w_ff2 = (const float*)d_in[9];
    const float* b_ff2 = (const float*)d_in[10];
    const float* ln2_g = (const float*)d_in[11];
    const float* ln2_b = (const float*)d_in[12];
    const float* lnf_g = (const float*)d_in[13];
    const float* lnf_b = (const float*)d_in[14];
    float* out = (float*)d_out;

    // ws map (bytes), total 13.4 MB:
    //   qswz [0, 3.15M)         Q fragment-major [b][h][tile][ks][lane][8]
    //   kswz [3.15M, 6.29M)     K fragment-major
    //   vbuf [6.29M, 9.44M)     V row-major [b][h][t][32]
    //   h1b  [9.44M, 12.58M)    bf16 LN1 output
    //   wts  [12.58M, 13.44M)   bf16 weights (fragment-major)
    char* wsb = (char*)d_ws;
    bf16*  qswz  = (bf16*)wsb;
    bf16*  kswz  = (bf16*)(wsb + 3145728);
    bf16*  vbuf  = (bf16*)(wsb + 6291456);
    bf16*  h1b   = (bf16*)(wsb + 9437184);
    bf16*  wts   = (bf16*)(wsb + 12582912);
    bf16*  wqs   = wts;
    bf16*  wos   = wts + 27648;
    bf16*  w1s   = wts + 36864;
    bf16*  w2s   = wts + 233472;

    cvtw_kernel   <<<1680, 256, 0, stream>>>(w_qkv, w_out, w_ff1, w_ff2, wts);
    qkv_kernel    <<<BT/32, 256, 0, stream>>>(x, wqs, b_qkv, qswz, kswz, vbuf);
    attn_op_kernel<<<B*(T/32), 192, 0, stream>>>(qswz, kswz, vbuf, wos, b_out, x,
                                                 ln1_g, ln1_b, h1b);
    ff_kernel     <<<BT/64, 256, 0, stream>>>(h1b, w1s, b_ff1, w2s, b_ff2,
                                              ln2_g, ln2_b, lnf_g, lnf_b, out);
}